// Round 7
// baseline (343.678 us; speedup 1.0000x reference)
//
#include <hip/hip_runtime.h>
#include <stdint.h>
#include <math.h>

#define DEVI __device__ __forceinline__
typedef unsigned short ushort_t;
typedef __attribute__((ext_vector_type(8))) __bf16 bf16x8;
typedef __attribute__((ext_vector_type(4))) float f32x4;

// ---------- scalar bf16 helpers (RNE, matches HW/harness encoding) ----------
DEVI float bf2f(ushort_t b){ union{uint32_t u; float f;} c; c.u = ((uint32_t)b) << 16; return c.f; }
DEVI ushort_t f2bf(float f){ union{float f; uint32_t u;} c; c.f = f; uint32_t u = c.u;
                             u += 0x7fffu + ((u >> 16) & 1u); return (ushort_t)(u >> 16); }

// fast tanh: 1 - 2/(exp2(2*log2e*x)+1). ~5 VALU ops, saturates correctly.
DEVI float fast_tanh(float x){
  float t = __builtin_amdgcn_exp2f(x * 2.8853900817779268f);
  return 1.0f - 2.0f * __builtin_amdgcn_rcpf(t + 1.0f);
}

// ---------- async global->LDS (16B per lane, dest = wave-uniform base + lane*16) ----------
DEVI void async16(const ushort_t* g, ushort_t* l){
  __builtin_amdgcn_global_load_lds((const __attribute__((address_space(1))) void*)g,
                                   (__attribute__((address_space(3))) void*)l, 16, 0, 0);
}

// ---------- problem constants ----------
#define BB 32768
#define INDIM 256
#define LATENT 128
#define HID 1024
#define KCODES 1024

// =====================================================================
// dtype sniffer: flag = 1 -> buffers are bf16 ; flag = 0 -> fp32
// =====================================================================
__global__ void k_sniff(const ushort_t* __restrict__ act, int* flag){
  if (threadIdx.x == 0){
    int bad = 0;
    for (int i = 0; i < 256; i++){
      float v = bf2f(act[i]);
      float a = fabsf(v);
      if (!(a <= 16.0f) || (a > 0.0f && a < 9.5e-7f)) bad++;
    }
    flag[0] = (bad >= 8) ? 0 : 1;
  }
}

// merged prep: action->bf16, emb->bf16, 6 biases->fp32, enorm, ONE launch.
__global__ void k_prep(const void* __restrict__ act_src, ushort_t* __restrict__ act_dst,
                       const void* __restrict__ emb_src, ushort_t* __restrict__ emb_dst,
                       const void* b0, const void* b1, const void* b2,
                       const void* b3, const void* b4, const void* b5,
                       float* __restrict__ biasf, float* __restrict__ enorm,
                       const int* __restrict__ flagp){
  const int f = *flagp;
  const int A8 = BB * INDIM / 8;
  const int E8 = KCODES * LATENT / 8;
  int i = blockIdx.x * blockDim.x + threadIdx.x;
  if (i < A8 + E8){
    const void* src; ushort_t* dst; int k;
    if (i < A8){ src = act_src; dst = act_dst; k = i; }
    else       { src = emb_src; dst = emb_dst; k = i - A8; }
    if (f){
      ((uint4*)dst)[k] = ((const uint4*)src)[k];
    } else {
      const float* s = (const float*)src + (size_t)k * 8;
      ushort_t o[8];
      #pragma unroll
      for (int j = 0; j < 8; j++) o[j] = f2bf(s[j]);
      ((uint4*)dst)[k] = *(const uint4*)o;
    }
  } else {
    int k = i - A8 - E8;
    if (k < 6144){
      int seg = k >> 10, off = k & 1023;
      const void* sp; int n;
      switch (seg){
        case 0: sp = b0; n = 1024; break;
        case 1: sp = b1; n = 1024; break;
        case 2: sp = b2; n = 128;  break;
        case 3: sp = b3; n = 1024; break;
        case 4: sp = b4; n = 1024; break;
        default: sp = b5; n = 256; break;
      }
      if (off < n)
        biasf[seg * 1024 + off] = f ? bf2f(((const ushort_t*)sp)[off]) : ((const float*)sp)[off];
    } else if (k < 6144 + KCODES){
      int c = k - 6144;
      float s = 0.f;
      if (f){
        const ushort_t* e = (const ushort_t*)emb_src + (long)c * LATENT;
        for (int d = 0; d < LATENT; d++){ float v = bf2f(e[d]); s += v * v; }
      } else {
        const float* e = (const float*)emb_src + (long)c * LATENT;
        for (int d = 0; d < LATENT; d++){ float v = bf2f(f2bf(e[d])); s += v * v; }
      }
      enorm[c] = s;
    }
  }
}

// all 6 weight transposes in ONE launch. src[R][C] -> dst[C][R] bf16.
__global__ void k_tcvt6(const void* s0, ushort_t* d0, const void* s1, ushort_t* d1,
                        const void* s2, ushort_t* d2, const void* s3, ushort_t* d3,
                        const void* s4, ushort_t* d4, const void* s5, ushort_t* d5,
                        const int* __restrict__ flagp){
  __shared__ ushort_t tile[32][33];
  int f = *flagp;
  int t = blockIdx.x;
  const void* src; ushort_t* dst; int R, C, lcx;
  if (t < 256)      { src=s0; dst=d0; R=256;  C=1024; lcx=5; }
  else if (t < 1280){ src=s1; dst=d1; R=1024; C=1024; lcx=5; t-=256;  }
  else if (t < 1408){ src=s2; dst=d2; R=1024; C=128;  lcx=2; t-=1280; }
  else if (t < 1536){ src=s3; dst=d3; R=128;  C=1024; lcx=5; t-=1408; }
  else if (t < 2560){ src=s4; dst=d4; R=1024; C=1024; lcx=5; t-=1536; }
  else              { src=s5; dst=d5; R=1024; C=256;  lcx=3; t-=2560; }
  int bx = t & ((C >> 5) - 1), by = t >> lcx;
  int tx = threadIdx.x & 31, ty = threadIdx.x >> 5;
  int c = bx * 32 + tx;
  #pragma unroll
  for (int ii = 0; ii < 4; ii++){
    int r = by * 32 + ty + ii * 8;
    long idx = (long)r * C + c;
    tile[ty + ii * 8][tx] = f ? ((const ushort_t*)src)[idx] : f2bf(((const float*)src)[idx]);
  }
  __syncthreads();
  #pragma unroll
  for (int ii = 0; ii < 4; ii++){
    int cc = bx * 32 + ty + ii * 8;
    dst[(long)cc * R + by * 32 + tx] = tile[tx][ty + ii * 8];
  }
}

// =====================================================================
// WIDE MFMA GEMM (N==1024): C = tanh(A[M,K] @ Bt[N,K]^T + b)
// 128x256 block tile, BK=64. TWO-SEGMENT launch with the SMALL segment
// FIRST (blocks [0,nsmall)): CP dispatches in roughly ascending blockIdx,
// so the tiny table GEMM starts at t=0 fully co-resident with the main
// segment instead of straggling at the tail (round-6 lesson: tail cost
// was ~20us). Per-element fold order (kb asc -> h -> MFMA) is
// M/grid-independent => outputs bit-identical to any segment split.
// =====================================================================
__global__ __launch_bounds__(256, 2)
void k_gemmw(const ushort_t* __restrict__ A, const ushort_t* __restrict__ Bt,
             const float* __restrict__ bias, int K,
             ushort_t* __restrict__ outb,
             int nsmall,
             const ushort_t* __restrict__ A2, const ushort_t* __restrict__ Bt2,
             const float* __restrict__ bias2, int K2,
             ushort_t* __restrict__ outb2)
{
  const int N = 1024;
  __shared__ __align__(16) ushort_t As[128 * 64];   // 16 KB
  __shared__ __align__(16) ushort_t Bs[256 * 64];   // 32 KB
  const int tid = threadIdx.x;
  const int w = tid >> 6, lane = tid & 63;
  const int lane15 = lane & 15, quad = lane >> 4;
  const int wr = w >> 1, wc = w & 1;

  int f = blockIdx.x;
  if (f < nsmall){ A = A2; Bt = Bt2; bias = bias2; K = K2; outb = outb2; }
  else f -= nsmall;

  const int j8 = f & 7, s = f >> 3;
  const int n_idx = s & 3;
  const int m_idx = ((s >> 2) << 3) | j8;
  const long m0 = (long)m_idx * 128;
  const int n0 = n_idx * 256;

  const int lrow = lane >> 3;
  const int lk8  = (((lane & 7) ^ (lrow & 7)) * 8);   // XOR-swizzled k-chunk
  const int rx   = lane15 & 7;

  f32x4 acc[4][8];
  #pragma unroll
  for (int i = 0; i < 4; i++)
    #pragma unroll
    for (int j = 0; j < 8; j++) acc[i][j] = (f32x4){0.f, 0.f, 0.f, 0.f};

  const int nk = K >> 6;
  for (int kb = 0; kb < nk; kb++){
    const int k0 = kb << 6;
    __syncthreads();
    #pragma unroll
    for (int a = 0; a < 4; a++){
      int m = w * 32 + a * 8 + lrow;
      async16(A + ((m0 + m) * K + k0 + lk8), &As[(w * 32 + a * 8) * 64]);
    }
    #pragma unroll
    for (int b = 0; b < 8; b++){
      int n = w * 64 + b * 8 + lrow;
      async16(Bt + ((long)(n0 + n) * K + k0 + lk8), &Bs[(w * 64 + b * 8) * 64]);
    }
    __builtin_amdgcn_s_waitcnt(0);
    __syncthreads();

    #pragma unroll
    for (int h = 0; h < 2; h++){
      bf16x8 af[4], bf[8];
      #pragma unroll
      for (int i = 0; i < 4; i++){
        int rho = wr * 64 + i * 16 + lane15;
        af[i] = *(const bf16x8*)&As[rho * 64 + ((((h << 2) | quad) ^ rx) * 8)];
      }
      #pragma unroll
      for (int j = 0; j < 8; j++){
        int rho = wc * 128 + j * 16 + lane15;
        bf[j] = *(const bf16x8*)&Bs[rho * 64 + ((((h << 2) | quad) ^ rx) * 8)];
      }
      #pragma unroll
      for (int i = 0; i < 4; i++)
        #pragma unroll
        for (int j = 0; j < 8; j++)
          acc[i][j] = __builtin_amdgcn_mfma_f32_16x16x32_bf16(af[i], bf[j], acc[i][j], 0, 0, 0);
    }
  }

  #pragma unroll
  for (int i = 0; i < 4; i++){
    int row_l = wr * 64 + i * 16 + quad * 4;
    #pragma unroll
    for (int j = 0; j < 8; j++){
      int col = n0 + wc * 128 + j * 16 + lane15;
      float b = bias[col];
      #pragma unroll
      for (int r = 0; r < 4; r++){
        float v = fast_tanh(acc[i][j][r] + b);
        outb[(m0 + row_l + r) * N + col] = f2bf(v);
      }
    }
  }
}

// =====================================================================
// FUSED: recon-table GEMM (blocks [0,16)) + z-GEMM + VQ (blocks [16,528)).
// Table first so it rides the full co-residency window (round-7 reorder).
// Main body: computes 64x128 z row-block (K=1024), writes z to d_out,
// stashes f2bf(z) into swizzled zt LDS, streams 8 codebook tiles,
// running argmax, writes zq + codes + loss partial.
// =====================================================================
__global__ __launch_bounds__(256)
void k_zvq(const ushort_t* __restrict__ A, const ushort_t* __restrict__ Bt,
           const float* __restrict__ bias, const ushort_t* __restrict__ embb,
           const float* __restrict__ enorm,
           int* __restrict__ codes, void* __restrict__ dout,
           long z_off, long zq_off,
           float* __restrict__ loss_part, const int* __restrict__ flagp,
           const ushort_t* __restrict__ tB, const ushort_t* __restrict__ dW2t,
           const float* __restrict__ bias3, float* __restrict__ rt)
{
  __shared__ __align__(16) ushort_t lds[24576];   // 48 KB
  __shared__ float lv[64][4];
  __shared__ int   li[64][4];
  __shared__ int   bi[64];
  __shared__ float red[4];

  const int tid = threadIdx.x;
  const int w = tid >> 6, lane = tid & 63;
  const int lane15 = lane & 15, quad = lane >> 4;
  const int wr = w >> 1, wc = w & 1;
  const int lrow = lane >> 3;
  const int rx   = lane15 & 7;

  // ---------------- table segment: rt = tB @ dW2t^T + b (f32) ----------------
  if (blockIdx.x < 16){
    ushort_t* As = lds;              // [64*64]   8 KB
    ushort_t* Bs = lds + 4096;       // [256*64] 32 KB
    const long m0 = (long)blockIdx.x * 64;
    const int lk8 = (((lane & 7) ^ lrow) << 3);

    f32x4 tacc[2][8];
    #pragma unroll
    for (int i = 0; i < 2; i++)
      #pragma unroll
      for (int j = 0; j < 8; j++) tacc[i][j] = (f32x4){0.f, 0.f, 0.f, 0.f};

    for (int kb = 0; kb < 16; kb++){
      const int k0 = kb << 6;
      __syncthreads();
      #pragma unroll
      for (int a = 0; a < 2; a++){
        int m = w * 16 + a * 8 + lrow;
        async16(tB + ((m0 + m) * 1024 + k0 + lk8), &As[(w * 16 + a * 8) * 64]);
      }
      #pragma unroll
      for (int b = 0; b < 8; b++){
        int n = w * 64 + b * 8 + lrow;
        async16(dW2t + ((long)n * 1024 + k0 + lk8), &Bs[(w * 64 + b * 8) * 64]);
      }
      __builtin_amdgcn_s_waitcnt(0);
      __syncthreads();

      #pragma unroll
      for (int h = 0; h < 2; h++){
        bf16x8 af[2], bf[8];
        #pragma unroll
        for (int i = 0; i < 2; i++){
          int rho = wr * 32 + i * 16 + lane15;
          af[i] = *(const bf16x8*)&As[rho * 64 + ((((h << 2) | quad) ^ rx) * 8)];
        }
        #pragma unroll
        for (int j = 0; j < 8; j++){
          int rho = wc * 128 + j * 16 + lane15;
          bf[j] = *(const bf16x8*)&Bs[rho * 64 + ((((h << 2) | quad) ^ rx) * 8)];
        }
        #pragma unroll
        for (int i = 0; i < 2; i++)
          #pragma unroll
          for (int j = 0; j < 8; j++)
            tacc[i][j] = __builtin_amdgcn_mfma_f32_16x16x32_bf16(af[i], bf[j], tacc[i][j], 0, 0, 0);
      }
    }
    #pragma unroll
    for (int i = 0; i < 2; i++){
      int row_l = wr * 32 + i * 16 + quad * 4;
      #pragma unroll
      for (int j = 0; j < 8; j++){
        int col = wc * 128 + j * 16 + lane15;
        float b = bias3[col];
        #pragma unroll
        for (int r = 0; r < 4; r++)
          rt[(m0 + row_l + r) * 256 + col] = tacc[i][j][r] + b;
      }
    }
    return;
  }

  ushort_t* As = lds;              // [64*64]   gemm phase
  ushort_t* Bs = lds + 4096;       // [128*64]  gemm phase
  ushort_t* zt = lds;              // [64*128]  vq phase
  ushort_t* et = lds + 8192;       // [128*128] vq phase

  const int f = blockIdx.x - 16;
  const int j8 = f & 7, s = f >> 3;
  const int m_idx = (s << 3) | j8;
  const long m0 = (long)m_idx * 64;
  const int lk8  = (((lane & 7) ^ lrow) << 3);

  // ---------------- phase 1: z = A[64x1024] @ Bt[128][1024]^T ----------------
  f32x4 acc[2][4];
  #pragma unroll
  for (int i = 0; i < 2; i++)
    #pragma unroll
    for (int j = 0; j < 4; j++) acc[i][j] = (f32x4){0.f, 0.f, 0.f, 0.f};

  for (int kb = 0; kb < 16; kb++){
    const int k0 = kb << 6;
    __syncthreads();
    #pragma unroll
    for (int a = 0; a < 2; a++){
      int m = w * 16 + a * 8 + lrow;
      async16(A + ((m0 + m) * 1024 + k0 + lk8), &As[(w * 16 + a * 8) * 64]);
    }
    #pragma unroll
    for (int b = 0; b < 4; b++){
      int n = w * 32 + b * 8 + lrow;
      async16(Bt + ((long)n * 1024 + k0 + lk8), &Bs[(w * 32 + b * 8) * 64]);
    }
    __builtin_amdgcn_s_waitcnt(0);
    __syncthreads();

    #pragma unroll
    for (int h = 0; h < 2; h++){
      bf16x8 af[2], bf[4];
      #pragma unroll
      for (int i = 0; i < 2; i++){
        int rho = wr * 32 + i * 16 + lane15;
        af[i] = *(const bf16x8*)&As[rho * 64 + ((((h << 2) | quad) ^ rx) * 8)];
      }
      #pragma unroll
      for (int j = 0; j < 4; j++){
        int rho = wc * 64 + j * 16 + lane15;
        bf[j] = *(const bf16x8*)&Bs[rho * 64 + ((((h << 2) | quad) ^ rx) * 8)];
      }
      #pragma unroll
      for (int i = 0; i < 2; i++)
        #pragma unroll
        for (int j = 0; j < 4; j++)
          acc[i][j] = __builtin_amdgcn_mfma_f32_16x16x32_bf16(af[i], bf[j], acc[i][j], 0, 0, 0);
    }
  }

  const int fl = *flagp;
  // z = acc + bias (kept in acc, f32); write z to d_out
  #pragma unroll
  for (int i = 0; i < 2; i++){
    int row_l = wr * 32 + i * 16 + quad * 4;
    #pragma unroll
    for (int j = 0; j < 4; j++){
      int col = wc * 64 + j * 16 + lane15;
      float b = bias[col];
      #pragma unroll
      for (int r = 0; r < 4; r++){
        float v = acc[i][j][r] + b;
        acc[i][j][r] = v;
        long idx = (m0 + row_l + r) * 128 + col;
        if (fl) ((ushort_t*)dout)[z_off + idx] = f2bf(v);
        else    ((float*)dout)[z_off + idx] = v;
      }
    }
  }

  __syncthreads();   // all ds_reads of As/Bs retired; LDS repurposed below

  // deposit f2bf(z) into zt with the k-chunk XOR swizzle
  #pragma unroll
  for (int i = 0; i < 2; i++){
    #pragma unroll
    for (int j = 0; j < 4; j++){
      int col = wc * 64 + j * 16 + lane15;
      int g = col >> 3, cw = col & 7;
      #pragma unroll
      for (int r = 0; r < 4; r++){
        int row_l = wr * 32 + i * 16 + quad * 4 + r;
        zt[row_l * 128 + ((g ^ (row_l & 15)) << 3) + cw] = f2bf(acc[i][j][r]);
      }
    }
  }
  // stage emb tile 0 (et region is disjoint from zt writes)
  const int srow = lane >> 4, schk = lane & 15;
  #pragma unroll
  for (int s8 = 0; s8 < 8; s8++){
    int r = w * 32 + s8 * 4 + srow;
    async16(embb + (long)r * 128 + ((schk ^ (r & 15)) * 8), &et[(w * 32 + s8 * 4) * 128]);
  }
  __builtin_amdgcn_s_waitcnt(0);
  __syncthreads();

  // ---------------- phase 2: VQ scores + running argmax ----------------
  float bestv[16];
  int   bestc[16];
  #pragma unroll
  for (int u = 0; u < 16; u++){ bestv[u] = -1e30f; bestc[u] = 0; }

  for (int t = 0; t < 8; t++){
    f32x4 sacc[4][2];
    #pragma unroll
    for (int i = 0; i < 4; i++){
      sacc[i][0] = (f32x4){0.f, 0.f, 0.f, 0.f};
      sacc[i][1] = (f32x4){0.f, 0.f, 0.f, 0.f};
    }
    #pragma unroll
    for (int ks = 0; ks < 4; ks++){
      bf16x8 af[4], bf[2];
      #pragma unroll
      for (int i = 0; i < 4; i++){
        int rho = i * 16 + lane15;
        af[i] = *(const bf16x8*)&zt[rho * 128 + ((((ks << 2) | quad) ^ (rho & 15)) * 8)];
      }
      #pragma unroll
      for (int j = 0; j < 2; j++){
        int rho = w * 32 + j * 16 + lane15;
        bf[j] = *(const bf16x8*)&et[rho * 128 + ((((ks << 2) | quad) ^ (rho & 15)) * 8)];
      }
      #pragma unroll
      for (int i = 0; i < 4; i++)
        #pragma unroll
        for (int j = 0; j < 2; j++)
          sacc[i][j] = __builtin_amdgcn_mfma_f32_16x16x32_bf16(af[i], bf[j], sacc[i][j], 0, 0, 0);
    }
    #pragma unroll
    for (int i = 0; i < 4; i++)
      #pragma unroll
      for (int r = 0; r < 4; r++)
        #pragma unroll
        for (int j = 0; j < 2; j++){
          int code = t * 128 + w * 32 + j * 16 + lane15;
          float v = sacc[i][j][r] - 0.5f * enorm[code];
          int u = i * 4 + r;
          if (v > bestv[u]){ bestv[u] = v; bestc[u] = code; }
        }
    if (t < 7){
      __syncthreads();
      #pragma unroll
      for (int s8 = 0; s8 < 8; s8++){
        int r = w * 32 + s8 * 4 + srow;
        async16(embb + ((long)(t + 1) * 128 + r) * 128 + ((schk ^ (r & 15)) * 8),
                &et[(w * 32 + s8 * 4) * 128]);
      }
      __builtin_amdgcn_s_waitcnt(0);
      __syncthreads();
    }
  }

  // per-wave argmax (16-lane groups hold 16 distinct codes per (i,r))
  #pragma unroll
  for (int i = 0; i < 4; i++)
    #pragma unroll
    for (int r = 0; r < 4; r++){
      float bv = bestv[i * 4 + r]; int bc = bestc[i * 4 + r];
      #pragma unroll
      for (int off = 1; off < 16; off <<= 1){
        float ov = __shfl_xor(bv, off, 64);
        int   oc = __shfl_xor(bc, off, 64);
        if (ov > bv || (ov == bv && oc < bc)){ bv = ov; bc = oc; }
      }
      if (lane15 == 0){
        int row_l = i * 16 + quad * 4 + r;
        lv[row_l][w] = bv; li[row_l][w] = bc;
      }
    }
  __syncthreads();
  if (tid < 64){
    float bv = lv[tid][0]; int bc = li[tid][0];
    #pragma unroll
    for (int ww = 1; ww < 4; ww++){
      float ov = lv[tid][ww]; int oc = li[tid][ww];
      if (ov > bv || (ov == bv && oc < bc)){ bv = ov; bc = oc; }
    }
    bi[tid] = bc;
    codes[m0 + tid] = bc;
  }
  __syncthreads();

  // ---------------- finalize: gather, zq writes, loss partial ----------------
  float p = 0.f;
  #pragma unroll
  for (int i = 0; i < 2; i++){
    #pragma unroll
    for (int j = 0; j < 4; j++){
      int col = wc * 64 + j * 16 + lane15;
      #pragma unroll
      for (int r = 0; r < 4; r++){
        int row_l = wr * 32 + i * 16 + quad * 4 + r;
        int code = bi[row_l];
        ushort_t qbits = embb[(long)code * LATENT + col];
        float qv = bf2f(qbits);
        long idx = (m0 + row_l) * LATENT + col;
        if (fl) ((ushort_t*)dout)[zq_off + idx] = qbits;
        else    ((float*)dout)[zq_off + idx] = qv;
        float diff = acc[i][j][r] - qv;
        p += diff * diff;
      }
    }
  }
  #pragma unroll
  for (int off = 32; off; off >>= 1) p += __shfl_down(p, off, 64);
  if ((tid & 63) == 0) red[tid >> 6] = p;
  __syncthreads();
  if (tid == 0) loss_part[f] = red[0] + red[1] + red[2] + red[3];
}

// =====================================================================
// recon gather + loss finalize fused: blocks [0,4096) gather
// out[row] = rt[codes[row]] (flag-dtype); block 4096 reduces loss_part
// (complete before this launch) -> d_out. One launch fewer.
// =====================================================================
__global__ __launch_bounds__(256)
void k_rgather(const float* __restrict__ rt, const int* __restrict__ codes,
               void* __restrict__ dout, const int* __restrict__ flagp,
               const float* __restrict__ loss_part, long l_off){
  const int fl = *flagp;
  if (blockIdx.x >= 4096){
    __shared__ float red[4];
    float s = 0.f;
    for (int i = threadIdx.x; i < 512; i += 256) s += loss_part[i];
    #pragma unroll
    for (int o = 32; o; o >>= 1) s += __shfl_down(s, o, 64);
    if ((threadIdx.x & 63) == 0) red[threadIdx.x >> 6] = s;
    __syncthreads();
    if (threadIdx.x == 0){
      float v = 1.25f * (red[0] + red[1] + red[2] + red[3]) / (float)((long)BB * LATENT);
      if (fl) ((ushort_t*)dout)[l_off] = f2bf(v);
      else    ((float*)dout)[l_off] = v;
    }
    return;
  }
  int row = blockIdx.x * 8 + (threadIdx.x >> 5);
  int c8 = (threadIdx.x & 31) * 8;
  int code = codes[row];
  const float* src = rt + (long)code * 256 + c8;
  float v[8];
  #pragma unroll
  for (int j = 0; j < 8; j++) v[j] = src[j];
  long base = (long)row * 256 + c8;
  if (fl){
    ushort_t o[8];
    #pragma unroll
    for (int j = 0; j < 8; j++) o[j] = f2bf(v[j]);
    *(uint4*)((ushort_t*)dout + base) = *(const uint4*)o;
  } else {
    float* d = (float*)dout + base;
    *(float4*)d = *(const float4*)v;
    *(float4*)(d + 4) = *(const float4*)(v + 4);
  }
}

// =====================================================================
extern "C" void kernel_launch(void* const* d_in, const int* in_sizes, int n_in,
                              void* d_out, int out_size, void* d_ws, size_t ws_size,
                              hipStream_t stream)
{
  (void)in_sizes; (void)n_in; (void)out_size; (void)ws_size;
  const void* action = d_in[1];
  const void* eW0 = d_in[2];  const void* eb0 = d_in[3];
  const void* eW1 = d_in[4];  const void* eb1 = d_in[5];
  const void* eW2 = d_in[6];  const void* eb2 = d_in[7];
  const void* emb = d_in[8];
  const void* dW0 = d_in[9];  const void* db0 = d_in[10];
  const void* dW1 = d_in[11]; const void* db1 = d_in[12];
  const void* dW2 = d_in[13]; const void* db2 = d_in[14];

  char* ws = (char*)d_ws;
  size_t off = 0;
  auto alloc = [&](size_t bytes)->char*{
    char* p = ws + off; off += bytes; off = (off + 255) & ~((size_t)255); return p;
  };
  int*      flag     = (int*)  alloc(4);
  float*    biasf    = (float*)alloc(6 * 1024 * 4);
  float*    enorm    = (float*)alloc(KCODES * 4);
  ushort_t* eW0t = (ushort_t*)alloc((size_t)HID * INDIM * 2);
  ushort_t* eW1t = (ushort_t*)alloc((size_t)HID * HID * 2);
  ushort_t* eW2t = (ushort_t*)alloc((size_t)LATENT * HID * 2);
  ushort_t* embb = (ushort_t*)alloc((size_t)KCODES * LATENT * 2);
  ushort_t* dW0t = (ushort_t*)alloc((size_t)HID * LATENT * 2);
  ushort_t* dW1t = (ushort_t*)alloc((size_t)HID * HID * 2);
  ushort_t* dW2t = (ushort_t*)alloc((size_t)INDIM * HID * 2);
  ushort_t* act0 = (ushort_t*)alloc((size_t)BB * INDIM * 2);
  ushort_t* hA   = (ushort_t*)alloc((size_t)BB * HID * 2);
  ushort_t* hB   = (ushort_t*)alloc((size_t)BB * HID * 2);
  ushort_t* tA   = (ushort_t*)alloc((size_t)KCODES * HID * 2);   // decoder table L0
  ushort_t* tB   = (ushort_t*)alloc((size_t)KCODES * HID * 2);   // decoder table L1
  float*    rt   = (float*)   alloc((size_t)KCODES * INDIM * 4); // recon table (f32)
  int*      codes = (int*)    alloc((size_t)BB * 4);
  float*    loss_part = (float*)alloc((size_t)512 * 4);

  const long z_off  = (long)BB * INDIM;
  const long zq_off = z_off + (long)BB * LATENT;
  const long l_off  = zq_off + (long)BB * LATENT;

  // ---- prep ----
  k_sniff<<<1, 64, 0, stream>>>((const ushort_t*)action, flag);
  {
    const int A8 = BB * INDIM / 8, E8 = KCODES * LATENT / 8;
    int total = A8 + E8 + 6144 + KCODES;
    k_prep<<<(total + 255) / 256, 256, 0, stream>>>(action, act0, emb, embb,
        eb0, eb1, eb2, db0, db1, db2, biasf, enorm, flag);
  }
  k_tcvt6<<<2816, 256, 0, stream>>>(eW0, eW0t, eW1, eW1t, eW2, eW2t,
                                    dW0, dW0t, dW1, dW1t, dW2, dW2t, flag);

  // ---- decoder table L0 (K=128, 32 blk FIRST) + enc-L0 (K=256, 1024 blk) ----
  k_gemmw<<<1056, 256, 0, stream>>>(act0, eW0t, biasf + 0, INDIM, hA,
      32, embb, dW0t, biasf + 3072, LATENT, tA);

  // ---- decoder table L1 (K=1024, 32 blk FIRST) + enc-L1 (K=1024, 1024 blk) ----
  k_gemmw<<<1056, 256, 0, stream>>>(hA, eW1t, biasf + 1024, HID, hB,
      32, tA, dW1t, biasf + 4096, HID, tB);

  // ---- recon table (16 blk FIRST) + fused z-GEMM + VQ (512 blk) ----
  k_zvq<<<528, 256, 0, stream>>>(hB, eW2t, biasf + 2048, embb, enorm,
      codes, d_out, z_off, zq_off, loss_part, flag,
      tB, dW2t, biasf + 5120, rt);

  // ---- decoder = table gather (+ loss finalize in last block) ----
  k_rgather<<<BB / 8 + 1, 256, 0, stream>>>(rt, codes, d_out, flag, loss_part, l_off);
}

// Round 8
// 327.500 us; speedup vs baseline: 1.0494x; 1.0494x over previous
//
#include <hip/hip_runtime.h>
#include <stdint.h>
#include <math.h>

#define DEVI __device__ __forceinline__
typedef unsigned short ushort_t;
typedef __attribute__((ext_vector_type(8))) __bf16 bf16x8;
typedef __attribute__((ext_vector_type(4))) float f32x4;

// ---------- scalar bf16 helpers (RNE, matches HW/harness encoding) ----------
DEVI float bf2f(ushort_t b){ union{uint32_t u; float f;} c; c.u = ((uint32_t)b) << 16; return c.f; }
DEVI ushort_t f2bf(float f){ union{float f; uint32_t u;} c; c.f = f; uint32_t u = c.u;
                             u += 0x7fffu + ((u >> 16) & 1u); return (ushort_t)(u >> 16); }

// fast tanh: 1 - 2/(exp2(2*log2e*x)+1). ~5 VALU ops, saturates correctly.
DEVI float fast_tanh(float x){
  float t = __builtin_amdgcn_exp2f(x * 2.8853900817779268f);
  return 1.0f - 2.0f * __builtin_amdgcn_rcpf(t + 1.0f);
}

// ---------- async global->LDS (16B per lane, dest = wave-uniform base + lane*16) ----------
DEVI void async16(const ushort_t* g, ushort_t* l){
  __builtin_amdgcn_global_load_lds((const __attribute__((address_space(1))) void*)g,
                                   (__attribute__((address_space(3))) void*)l, 16, 0, 0);
}

// ---------- problem constants ----------
#define BB 32768
#define INDIM 256
#define LATENT 128
#define HID 1024
#define KCODES 1024

// =====================================================================
// MERGED PREP (one launch, was 3: sniff + cvt/bias/enorm + tcvt6).
// Every block computes the dtype flag locally (wave-parallel over
// action[0..255], identical count/threshold to the old k_sniff =>
// identical flag); block 0 publishes it for the later kernels.
// Blocks [0,2816): the 6 weight transposes (tile counts 256,1024,128,
// 128,1024,256). Blocks [2816,...): action->bf16, emb->bf16, biases,
// enorm segments.
// =====================================================================
#define NTCVT 2816
__global__ void k_prep(const ushort_t* __restrict__ act16,
                       const void* __restrict__ act_src, ushort_t* __restrict__ act_dst,
                       const void* __restrict__ emb_src, ushort_t* __restrict__ emb_dst,
                       const void* b0, const void* b1, const void* b2,
                       const void* b3, const void* b4, const void* b5,
                       float* __restrict__ biasf, float* __restrict__ enorm,
                       const void* s0, ushort_t* d0, const void* s1, ushort_t* d1,
                       const void* s2, ushort_t* d2, const void* s3, ushort_t* d3,
                       const void* s4, ushort_t* d4, const void* s5, ushort_t* d5,
                       int* flagp){
  __shared__ ushort_t tile[32][33];
  __shared__ int redb[4];
  const int tid = threadIdx.x;

  // ---- local dtype flag (identical logic to old k_sniff) ----
  int bad = 0;
  {
    float v = bf2f(act16[tid]);        // tid in [0,256): one probe elem each
    float a = fabsf(v);
    if (!(a <= 16.0f) || (a > 0.0f && a < 9.5e-7f)) bad = 1;
  }
  #pragma unroll
  for (int o = 32; o; o >>= 1) bad += __shfl_down(bad, o, 64);
  if ((tid & 63) == 0) redb[tid >> 6] = bad;
  __syncthreads();
  const int f = ((redb[0] + redb[1] + redb[2] + redb[3]) >= 8) ? 0 : 1;
  if (blockIdx.x == 0 && tid == 0) flagp[0] = f;
  __syncthreads();   // protect tile[] reuse below

  if (blockIdx.x < NTCVT){
    // ---------------- transpose segment ----------------
    int t = blockIdx.x;
    const void* src; ushort_t* dst; int R, C, lcx;
    if (t < 256)      { src=s0; dst=d0; R=256;  C=1024; lcx=5; }
    else if (t < 1280){ src=s1; dst=d1; R=1024; C=1024; lcx=5; t-=256;  }
    else if (t < 1408){ src=s2; dst=d2; R=1024; C=128;  lcx=2; t-=1280; }
    else if (t < 1536){ src=s3; dst=d3; R=128;  C=1024; lcx=5; t-=1408; }
    else if (t < 2560){ src=s4; dst=d4; R=1024; C=1024; lcx=5; t-=1536; }
    else              { src=s5; dst=d5; R=1024; C=256;  lcx=3; t-=2560; }
    int bx = t & ((C >> 5) - 1), by = t >> lcx;
    int tx = tid & 31, ty = tid >> 5;
    int c = bx * 32 + tx;
    #pragma unroll
    for (int ii = 0; ii < 4; ii++){
      int r = by * 32 + ty + ii * 8;
      long idx = (long)r * C + c;
      tile[ty + ii * 8][tx] = f ? ((const ushort_t*)src)[idx] : f2bf(((const float*)src)[idx]);
    }
    __syncthreads();
    #pragma unroll
    for (int ii = 0; ii < 4; ii++){
      int cc = bx * 32 + ty + ii * 8;
      dst[(long)cc * R + by * 32 + tx] = tile[tx][ty + ii * 8];
    }
    return;
  }

  // ---------------- cvt / bias / enorm segments ----------------
  const int A8 = BB * INDIM / 8;
  const int E8 = KCODES * LATENT / 8;
  int i = (blockIdx.x - NTCVT) * blockDim.x + tid;
  if (i < A8 + E8){
    const void* src; ushort_t* dst; int k;
    if (i < A8){ src = act_src; dst = act_dst; k = i; }
    else       { src = emb_src; dst = emb_dst; k = i - A8; }
    if (f){
      ((uint4*)dst)[k] = ((const uint4*)src)[k];
    } else {
      const float* s = (const float*)src + (size_t)k * 8;
      ushort_t o[8];
      #pragma unroll
      for (int j = 0; j < 8; j++) o[j] = f2bf(s[j]);
      ((uint4*)dst)[k] = *(const uint4*)o;
    }
  } else {
    int k = i - A8 - E8;
    if (k < 6144){
      int seg = k >> 10, off = k & 1023;
      const void* sp; int n;
      switch (seg){
        case 0: sp = b0; n = 1024; break;
        case 1: sp = b1; n = 1024; break;
        case 2: sp = b2; n = 128;  break;
        case 3: sp = b3; n = 1024; break;
        case 4: sp = b4; n = 1024; break;
        default: sp = b5; n = 256; break;
      }
      if (off < n)
        biasf[seg * 1024 + off] = f ? bf2f(((const ushort_t*)sp)[off]) : ((const float*)sp)[off];
    } else if (k < 6144 + KCODES){
      int c = k - 6144;
      float s = 0.f;
      if (f){
        const ushort_t* e = (const ushort_t*)emb_src + (long)c * LATENT;
        for (int d = 0; d < LATENT; d++){ float v = bf2f(e[d]); s += v * v; }
      } else {
        const float* e = (const float*)emb_src + (long)c * LATENT;
        for (int d = 0; d < LATENT; d++){ float v = bf2f(f2bf(e[d])); s += v * v; }
      }
      enorm[c] = s;
    }
  }
}

// =====================================================================
// WIDE MFMA GEMM (N==1024): C = tanh(A[M,K] @ Bt[N,K]^T + b)
// 128x256 block tile, BK=64. TWO-SEGMENT launch, SMALL SEGMENT LAST
// (round-7 A/B: small-first costs +8MB fetch, no makespan gain).
// Per-element fold order (kb asc -> h -> MFMA) is M/grid-independent
// => outputs bit-identical to any segment split.
// =====================================================================
__global__ __launch_bounds__(256, 2)
void k_gemmw(const ushort_t* __restrict__ A, const ushort_t* __restrict__ Bt,
             const float* __restrict__ bias, int K,
             ushort_t* __restrict__ outb,
             int nblk1,
             const ushort_t* __restrict__ A2, const ushort_t* __restrict__ Bt2,
             const float* __restrict__ bias2, int K2,
             ushort_t* __restrict__ outb2)
{
  const int N = 1024;
  __shared__ __align__(16) ushort_t As[128 * 64];   // 16 KB
  __shared__ __align__(16) ushort_t Bs[256 * 64];   // 32 KB
  const int tid = threadIdx.x;
  const int w = tid >> 6, lane = tid & 63;
  const int lane15 = lane & 15, quad = lane >> 4;
  const int wr = w >> 1, wc = w & 1;

  int f = blockIdx.x;
  if (f >= nblk1){ A = A2; Bt = Bt2; bias = bias2; K = K2; outb = outb2; f -= nblk1; }

  const int j8 = f & 7, s = f >> 3;
  const int n_idx = s & 3;
  const int m_idx = ((s >> 2) << 3) | j8;
  const long m0 = (long)m_idx * 128;
  const int n0 = n_idx * 256;

  const int lrow = lane >> 3;
  const int lk8  = (((lane & 7) ^ (lrow & 7)) * 8);   // XOR-swizzled k-chunk
  const int rx   = lane15 & 7;

  f32x4 acc[4][8];
  #pragma unroll
  for (int i = 0; i < 4; i++)
    #pragma unroll
    for (int j = 0; j < 8; j++) acc[i][j] = (f32x4){0.f, 0.f, 0.f, 0.f};

  const int nk = K >> 6;
  for (int kb = 0; kb < nk; kb++){
    const int k0 = kb << 6;
    __syncthreads();
    #pragma unroll
    for (int a = 0; a < 4; a++){
      int m = w * 32 + a * 8 + lrow;
      async16(A + ((m0 + m) * K + k0 + lk8), &As[(w * 32 + a * 8) * 64]);
    }
    #pragma unroll
    for (int b = 0; b < 8; b++){
      int n = w * 64 + b * 8 + lrow;
      async16(Bt + ((long)(n0 + n) * K + k0 + lk8), &Bs[(w * 64 + b * 8) * 64]);
    }
    __builtin_amdgcn_s_waitcnt(0);
    __syncthreads();

    #pragma unroll
    for (int h = 0; h < 2; h++){
      bf16x8 af[4], bf[8];
      #pragma unroll
      for (int i = 0; i < 4; i++){
        int rho = wr * 64 + i * 16 + lane15;
        af[i] = *(const bf16x8*)&As[rho * 64 + ((((h << 2) | quad) ^ rx) * 8)];
      }
      #pragma unroll
      for (int j = 0; j < 8; j++){
        int rho = wc * 128 + j * 16 + lane15;
        bf[j] = *(const bf16x8*)&Bs[rho * 64 + ((((h << 2) | quad) ^ rx) * 8)];
      }
      #pragma unroll
      for (int i = 0; i < 4; i++)
        #pragma unroll
        for (int j = 0; j < 8; j++)
          acc[i][j] = __builtin_amdgcn_mfma_f32_16x16x32_bf16(af[i], bf[j], acc[i][j], 0, 0, 0);
    }
  }

  #pragma unroll
  for (int i = 0; i < 4; i++){
    int row_l = wr * 64 + i * 16 + quad * 4;
    #pragma unroll
    for (int j = 0; j < 8; j++){
      int col = n0 + wc * 128 + j * 16 + lane15;
      float b = bias[col];
      #pragma unroll
      for (int r = 0; r < 4; r++){
        float v = fast_tanh(acc[i][j][r] + b);
        outb[(m0 + row_l + r) * N + col] = f2bf(v);
      }
    }
  }
}

// =====================================================================
// FUSED z-GEMM + VQ (blocks [0,512)) + recon-table GEMM (blocks [512,528)).
// Main body: computes 64x128 z row-block (K=1024), writes z to d_out,
// stashes f2bf(z) into swizzled zt LDS, streams 8 codebook tiles,
// running argmax, writes zq + codes + loss partial.
// Table body: rt[1024][256] = tB@dW2t^T + b in f32 (64x256 tile, BK=64).
// =====================================================================
__global__ __launch_bounds__(256)
void k_zvq(const ushort_t* __restrict__ A, const ushort_t* __restrict__ Bt,
           const float* __restrict__ bias, const ushort_t* __restrict__ embb,
           const float* __restrict__ enorm,
           int* __restrict__ codes, void* __restrict__ dout,
           long z_off, long zq_off,
           float* __restrict__ loss_part, const int* __restrict__ flagp,
           const ushort_t* __restrict__ tB, const ushort_t* __restrict__ dW2t,
           const float* __restrict__ bias3, float* __restrict__ rt)
{
  __shared__ __align__(16) ushort_t lds[24576];   // 48 KB
  __shared__ float lv[64][4];
  __shared__ int   li[64][4];
  __shared__ int   bi[64];
  __shared__ float red[4];

  const int tid = threadIdx.x;
  const int w = tid >> 6, lane = tid & 63;
  const int lane15 = lane & 15, quad = lane >> 4;
  const int wr = w >> 1, wc = w & 1;
  const int lrow = lane >> 3;
  const int rx   = lane15 & 7;

  // ---------------- table segment: rt = tB @ dW2t^T + b (f32) ----------------
  if (blockIdx.x >= 512){
    ushort_t* As = lds;              // [64*64]   8 KB
    ushort_t* Bs = lds + 4096;       // [256*64] 32 KB
    const long m0 = (long)(blockIdx.x - 512) * 64;
    const int lk8 = (((lane & 7) ^ lrow) << 3);

    f32x4 tacc[2][8];
    #pragma unroll
    for (int i = 0; i < 2; i++)
      #pragma unroll
      for (int j = 0; j < 8; j++) tacc[i][j] = (f32x4){0.f, 0.f, 0.f, 0.f};

    for (int kb = 0; kb < 16; kb++){
      const int k0 = kb << 6;
      __syncthreads();
      #pragma unroll
      for (int a = 0; a < 2; a++){
        int m = w * 16 + a * 8 + lrow;
        async16(tB + ((m0 + m) * 1024 + k0 + lk8), &As[(w * 16 + a * 8) * 64]);
      }
      #pragma unroll
      for (int b = 0; b < 8; b++){
        int n = w * 64 + b * 8 + lrow;
        async16(dW2t + ((long)n * 1024 + k0 + lk8), &Bs[(w * 64 + b * 8) * 64]);
      }
      __builtin_amdgcn_s_waitcnt(0);
      __syncthreads();

      #pragma unroll
      for (int h = 0; h < 2; h++){
        bf16x8 af[2], bf[8];
        #pragma unroll
        for (int i = 0; i < 2; i++){
          int rho = wr * 32 + i * 16 + lane15;
          af[i] = *(const bf16x8*)&As[rho * 64 + ((((h << 2) | quad) ^ rx) * 8)];
        }
        #pragma unroll
        for (int j = 0; j < 8; j++){
          int rho = wc * 128 + j * 16 + lane15;
          bf[j] = *(const bf16x8*)&Bs[rho * 64 + ((((h << 2) | quad) ^ rx) * 8)];
        }
        #pragma unroll
        for (int i = 0; i < 2; i++)
          #pragma unroll
          for (int j = 0; j < 8; j++)
            tacc[i][j] = __builtin_amdgcn_mfma_f32_16x16x32_bf16(af[i], bf[j], tacc[i][j], 0, 0, 0);
      }
    }
    #pragma unroll
    for (int i = 0; i < 2; i++){
      int row_l = wr * 32 + i * 16 + quad * 4;
      #pragma unroll
      for (int j = 0; j < 8; j++){
        int col = wc * 128 + j * 16 + lane15;
        float b = bias3[col];
        #pragma unroll
        for (int r = 0; r < 4; r++)
          rt[(m0 + row_l + r) * 256 + col] = tacc[i][j][r] + b;
      }
    }
    return;
  }

  ushort_t* As = lds;              // [64*64]   gemm phase
  ushort_t* Bs = lds + 4096;       // [128*64]  gemm phase
  ushort_t* zt = lds;              // [64*128]  vq phase
  ushort_t* et = lds + 8192;       // [128*128] vq phase

  const int f = blockIdx.x;
  const int j8 = f & 7, s = f >> 3;
  const int m_idx = (s << 3) | j8;
  const long m0 = (long)m_idx * 64;
  const int lk8  = (((lane & 7) ^ lrow) << 3);

  // ---------------- phase 1: z = A[64x1024] @ Bt[128][1024]^T ----------------
  f32x4 acc[2][4];
  #pragma unroll
  for (int i = 0; i < 2; i++)
    #pragma unroll
    for (int j = 0; j < 4; j++) acc[i][j] = (f32x4){0.f, 0.f, 0.f, 0.f};

  for (int kb = 0; kb < 16; kb++){
    const int k0 = kb << 6;
    __syncthreads();
    #pragma unroll
    for (int a = 0; a < 2; a++){
      int m = w * 16 + a * 8 + lrow;
      async16(A + ((m0 + m) * 1024 + k0 + lk8), &As[(w * 16 + a * 8) * 64]);
    }
    #pragma unroll
    for (int b = 0; b < 4; b++){
      int n = w * 32 + b * 8 + lrow;
      async16(Bt + ((long)n * 1024 + k0 + lk8), &Bs[(w * 32 + b * 8) * 64]);
    }
    __builtin_amdgcn_s_waitcnt(0);
    __syncthreads();

    #pragma unroll
    for (int h = 0; h < 2; h++){
      bf16x8 af[2], bf[4];
      #pragma unroll
      for (int i = 0; i < 2; i++){
        int rho = wr * 32 + i * 16 + lane15;
        af[i] = *(const bf16x8*)&As[rho * 64 + ((((h << 2) | quad) ^ rx) * 8)];
      }
      #pragma unroll
      for (int j = 0; j < 4; j++){
        int rho = wc * 64 + j * 16 + lane15;
        bf[j] = *(const bf16x8*)&Bs[rho * 64 + ((((h << 2) | quad) ^ rx) * 8)];
      }
      #pragma unroll
      for (int i = 0; i < 2; i++)
        #pragma unroll
        for (int j = 0; j < 4; j++)
          acc[i][j] = __builtin_amdgcn_mfma_f32_16x16x32_bf16(af[i], bf[j], acc[i][j], 0, 0, 0);
    }
  }

  const int fl = *flagp;
  // z = acc + bias (kept in acc, f32); write z to d_out
  #pragma unroll
  for (int i = 0; i < 2; i++){
    int row_l = wr * 32 + i * 16 + quad * 4;
    #pragma unroll
    for (int j = 0; j < 4; j++){
      int col = wc * 64 + j * 16 + lane15;
      float b = bias[col];
      #pragma unroll
      for (int r = 0; r < 4; r++){
        float v = acc[i][j][r] + b;
        acc[i][j][r] = v;
        long idx = (m0 + row_l + r) * 128 + col;
        if (fl) ((ushort_t*)dout)[z_off + idx] = f2bf(v);
        else    ((float*)dout)[z_off + idx] = v;
      }
    }
  }

  __syncthreads();   // all ds_reads of As/Bs retired; LDS repurposed below

  // deposit f2bf(z) into zt with the k-chunk XOR swizzle
  #pragma unroll
  for (int i = 0; i < 2; i++){
    #pragma unroll
    for (int j = 0; j < 4; j++){
      int col = wc * 64 + j * 16 + lane15;
      int g = col >> 3, cw = col & 7;
      #pragma unroll
      for (int r = 0; r < 4; r++){
        int row_l = wr * 32 + i * 16 + quad * 4 + r;
        zt[row_l * 128 + ((g ^ (row_l & 15)) << 3) + cw] = f2bf(acc[i][j][r]);
      }
    }
  }
  // stage emb tile 0 (et region is disjoint from zt writes)
  const int srow = lane >> 4, schk = lane & 15;
  #pragma unroll
  for (int s8 = 0; s8 < 8; s8++){
    int r = w * 32 + s8 * 4 + srow;
    async16(embb + (long)r * 128 + ((schk ^ (r & 15)) * 8), &et[(w * 32 + s8 * 4) * 128]);
  }
  __builtin_amdgcn_s_waitcnt(0);
  __syncthreads();

  // ---------------- phase 2: VQ scores + running argmax ----------------
  float bestv[16];
  int   bestc[16];
  #pragma unroll
  for (int u = 0; u < 16; u++){ bestv[u] = -1e30f; bestc[u] = 0; }

  for (int t = 0; t < 8; t++){
    f32x4 sacc[4][2];
    #pragma unroll
    for (int i = 0; i < 4; i++){
      sacc[i][0] = (f32x4){0.f, 0.f, 0.f, 0.f};
      sacc[i][1] = (f32x4){0.f, 0.f, 0.f, 0.f};
    }
    #pragma unroll
    for (int ks = 0; ks < 4; ks++){
      bf16x8 af[4], bf[2];
      #pragma unroll
      for (int i = 0; i < 4; i++){
        int rho = i * 16 + lane15;
        af[i] = *(const bf16x8*)&zt[rho * 128 + ((((ks << 2) | quad) ^ (rho & 15)) * 8)];
      }
      #pragma unroll
      for (int j = 0; j < 2; j++){
        int rho = w * 32 + j * 16 + lane15;
        bf[j] = *(const bf16x8*)&et[rho * 128 + ((((ks << 2) | quad) ^ (rho & 15)) * 8)];
      }
      #pragma unroll
      for (int i = 0; i < 4; i++)
        #pragma unroll
        for (int j = 0; j < 2; j++)
          sacc[i][j] = __builtin_amdgcn_mfma_f32_16x16x32_bf16(af[i], bf[j], sacc[i][j], 0, 0, 0);
    }
    #pragma unroll
    for (int i = 0; i < 4; i++)
      #pragma unroll
      for (int r = 0; r < 4; r++)
        #pragma unroll
        for (int j = 0; j < 2; j++){
          int code = t * 128 + w * 32 + j * 16 + lane15;
          float v = sacc[i][j][r] - 0.5f * enorm[code];
          int u = i * 4 + r;
          if (v > bestv[u]){ bestv[u] = v; bestc[u] = code; }
        }
    if (t < 7){
      __syncthreads();
      #pragma unroll
      for (int s8 = 0; s8 < 8; s8++){
        int r = w * 32 + s8 * 4 + srow;
        async16(embb + ((long)(t + 1) * 128 + r) * 128 + ((schk ^ (r & 15)) * 8),
                &et[(w * 32 + s8 * 4) * 128]);
      }
      __builtin_amdgcn_s_waitcnt(0);
      __syncthreads();
    }
  }

  // per-wave argmax (16-lane groups hold 16 distinct codes per (i,r))
  #pragma unroll
  for (int i = 0; i < 4; i++)
    #pragma unroll
    for (int r = 0; r < 4; r++){
      float bv = bestv[i * 4 + r]; int bc = bestc[i * 4 + r];
      #pragma unroll
      for (int off = 1; off < 16; off <<= 1){
        float ov = __shfl_xor(bv, off, 64);
        int   oc = __shfl_xor(bc, off, 64);
        if (ov > bv || (ov == bv && oc < bc)){ bv = ov; bc = oc; }
      }
      if (lane15 == 0){
        int row_l = i * 16 + quad * 4 + r;
        lv[row_l][w] = bv; li[row_l][w] = bc;
      }
    }
  __syncthreads();
  if (tid < 64){
    float bv = lv[tid][0]; int bc = li[tid][0];
    #pragma unroll
    for (int ww = 1; ww < 4; ww++){
      float ov = lv[tid][ww]; int oc = li[tid][ww];
      if (ov > bv || (ov == bv && oc < bc)){ bv = ov; bc = oc; }
    }
    bi[tid] = bc;
    codes[m0 + tid] = bc;
  }
  __syncthreads();

  // ---------------- finalize: gather, zq writes, loss partial ----------------
  float p = 0.f;
  #pragma unroll
  for (int i = 0; i < 2; i++){
    #pragma unroll
    for (int j = 0; j < 4; j++){
      int col = wc * 64 + j * 16 + lane15;
      #pragma unroll
      for (int r = 0; r < 4; r++){
        int row_l = wr * 32 + i * 16 + quad * 4 + r;
        int code = bi[row_l];
        ushort_t qbits = embb[(long)code * LATENT + col];
        float qv = bf2f(qbits);
        long idx = (m0 + row_l) * LATENT + col;
        if (fl) ((ushort_t*)dout)[zq_off + idx] = qbits;
        else    ((float*)dout)[zq_off + idx] = qv;
        float diff = acc[i][j][r] - qv;
        p += diff * diff;
      }
    }
  }
  #pragma unroll
  for (int off = 32; off; off >>= 1) p += __shfl_down(p, off, 64);
  if ((tid & 63) == 0) red[tid >> 6] = p;
  __syncthreads();
  if (tid == 0) loss_part[blockIdx.x] = red[0] + red[1] + red[2] + red[3];
}

// =====================================================================
// recon gather + loss finalize fused: blocks [0,4096) gather
// out[row] = rt[codes[row]] (flag-dtype); block 4096 reduces loss_part
// (complete before this launch) -> d_out.
// =====================================================================
__global__ __launch_bounds__(256)
void k_rgather(const float* __restrict__ rt, const int* __restrict__ codes,
               void* __restrict__ dout, const int* __restrict__ flagp,
               const float* __restrict__ loss_part, long l_off){
  const int fl = *flagp;
  if (blockIdx.x >= 4096){
    __shared__ float red[4];
    float s = 0.f;
    for (int i = threadIdx.x; i < 512; i += 256) s += loss_part[i];
    #pragma unroll
    for (int o = 32; o; o >>= 1) s += __shfl_down(s, o, 64);
    if ((threadIdx.x & 63) == 0) red[threadIdx.x >> 6] = s;
    __syncthreads();
    if (threadIdx.x == 0){
      float v = 1.25f * (red[0] + red[1] + red[2] + red[3]) / (float)((long)BB * LATENT);
      if (fl) ((ushort_t*)dout)[l_off] = f2bf(v);
      else    ((float*)dout)[l_off] = v;
    }
    return;
  }
  int row = blockIdx.x * 8 + (threadIdx.x >> 5);
  int c8 = (threadIdx.x & 31) * 8;
  int code = codes[row];
  const float* src = rt + (long)code * 256 + c8;
  float v[8];
  #pragma unroll
  for (int j = 0; j < 8; j++) v[j] = src[j];
  long base = (long)row * 256 + c8;
  if (fl){
    ushort_t o[8];
    #pragma unroll
    for (int j = 0; j < 8; j++) o[j] = f2bf(v[j]);
    *(uint4*)((ushort_t*)dout + base) = *(const uint4*)o;
  } else {
    float* d = (float*)dout + base;
    *(float4*)d = *(const float4*)v;
    *(float4*)(d + 4) = *(const float4*)(v + 4);
  }
}

// =====================================================================
extern "C" void kernel_launch(void* const* d_in, const int* in_sizes, int n_in,
                              void* d_out, int out_size, void* d_ws, size_t ws_size,
                              hipStream_t stream)
{
  (void)in_sizes; (void)n_in; (void)out_size; (void)ws_size;
  const void* action = d_in[1];
  const void* eW0 = d_in[2];  const void* eb0 = d_in[3];
  const void* eW1 = d_in[4];  const void* eb1 = d_in[5];
  const void* eW2 = d_in[6];  const void* eb2 = d_in[7];
  const void* emb = d_in[8];
  const void* dW0 = d_in[9];  const void* db0 = d_in[10];
  const void* dW1 = d_in[11]; const void* db1 = d_in[12];
  const void* dW2 = d_in[13]; const void* db2 = d_in[14];

  char* ws = (char*)d_ws;
  size_t off = 0;
  auto alloc = [&](size_t bytes)->char*{
    char* p = ws + off; off += bytes; off = (off + 255) & ~((size_t)255); return p;
  };
  int*      flag     = (int*)  alloc(4);
  float*    biasf    = (float*)alloc(6 * 1024 * 4);
  float*    enorm    = (float*)alloc(KCODES * 4);
  ushort_t* eW0t = (ushort_t*)alloc((size_t)HID * INDIM * 2);
  ushort_t* eW1t = (ushort_t*)alloc((size_t)HID * HID * 2);
  ushort_t* eW2t = (ushort_t*)alloc((size_t)LATENT * HID * 2);
  ushort_t* embb = (ushort_t*)alloc((size_t)KCODES * LATENT * 2);
  ushort_t* dW0t = (ushort_t*)alloc((size_t)HID * LATENT * 2);
  ushort_t* dW1t = (ushort_t*)alloc((size_t)HID * HID * 2);
  ushort_t* dW2t = (ushort_t*)alloc((size_t)INDIM * HID * 2);
  ushort_t* act0 = (ushort_t*)alloc((size_t)BB * INDIM * 2);
  ushort_t* hA   = (ushort_t*)alloc((size_t)BB * HID * 2);
  ushort_t* hB   = (ushort_t*)alloc((size_t)BB * HID * 2);
  ushort_t* tA   = (ushort_t*)alloc((size_t)KCODES * HID * 2);   // decoder table L0
  ushort_t* tB   = (ushort_t*)alloc((size_t)KCODES * HID * 2);   // decoder table L1
  float*    rt   = (float*)   alloc((size_t)KCODES * INDIM * 4); // recon table (f32)
  int*      codes = (int*)    alloc((size_t)BB * 4);
  float*    loss_part = (float*)alloc((size_t)512 * 4);

  const long z_off  = (long)BB * INDIM;
  const long zq_off = z_off + (long)BB * LATENT;
  const long l_off  = zq_off + (long)BB * LATENT;

  // ---- merged prep: transposes + cvt + bias + enorm + dtype flag (1 launch) ----
  {
    const int A8 = BB * INDIM / 8, E8 = KCODES * LATENT / 8;
    int nprep = (A8 + E8 + 6144 + KCODES + 255) / 256;
    k_prep<<<NTCVT + nprep, 256, 0, stream>>>((const ushort_t*)action,
        action, act0, emb, embb,
        eb0, eb1, eb2, db0, db1, db2, biasf, enorm,
        eW0, eW0t, eW1, eW1t, eW2, eW2t,
        dW0, dW0t, dW1, dW1t, dW2, dW2t, flag);
  }

  // ---- enc-L0 (K=256, 1024 blk) + decoder table L0 (K=128, 32 blk LAST) ----
  k_gemmw<<<1056, 256, 0, stream>>>(act0, eW0t, biasf + 0, INDIM, hA,
      1024, embb, dW0t, biasf + 3072, LATENT, tA);

  // ---- enc-L1 (K=1024, 1024 blk) + decoder table L1 (K=1024, 32 blk LAST) ----
  k_gemmw<<<1056, 256, 0, stream>>>(hA, eW1t, biasf + 1024, HID, hB,
      1024, tA, dW1t, biasf + 4096, HID, tB);

  // ---- fused z-GEMM + VQ (512 blk) + recon table (16 blk LAST) ----
  k_zvq<<<528, 256, 0, stream>>>(hB, eW2t, biasf + 2048, embb, enorm,
      codes, d_out, z_off, zq_off, loss_part, flag,
      tB, dW2t, biasf + 5120, rt);

  // ---- decoder = table gather (+ loss finalize in last block) ----
  k_rgather<<<BB / 8 + 1, 256, 0, stream>>>(rt, codes, d_out, flag, loss_part, l_off);
}

// Round 9
// 298.086 us; speedup vs baseline: 1.1529x; 1.0987x over previous
//
#include <hip/hip_runtime.h>
#include <stdint.h>
#include <math.h>

#define DEVI __device__ __forceinline__
typedef unsigned short ushort_t;
typedef __attribute__((ext_vector_type(8))) __bf16 bf16x8;
typedef __attribute__((ext_vector_type(4))) float f32x4;

// ---------- scalar bf16 helpers (RNE, matches HW/harness encoding) ----------
DEVI float bf2f(ushort_t b){ union{uint32_t u; float f;} c; c.u = ((uint32_t)b) << 16; return c.f; }
DEVI ushort_t f2bf(float f){ union{float f; uint32_t u;} c; c.f = f; uint32_t u = c.u;
                             u += 0x7fffu + ((u >> 16) & 1u); return (ushort_t)(u >> 16); }

// fast tanh: 1 - 2/(exp2(2*log2e*x)+1). ~5 VALU ops, saturates correctly.
DEVI float fast_tanh(float x){
  float t = __builtin_amdgcn_exp2f(x * 2.8853900817779268f);
  return 1.0f - 2.0f * __builtin_amdgcn_rcpf(t + 1.0f);
}

// ---------- async global->LDS (16B per lane, dest = wave-uniform base + lane*16) ----------
DEVI void async16(const ushort_t* g, ushort_t* l){
  __builtin_amdgcn_global_load_lds((const __attribute__((address_space(1))) void*)g,
                                   (__attribute__((address_space(3))) void*)l, 16, 0, 0);
}

// ---------- problem constants ----------
#define BB 32768
#define INDIM 256
#define LATENT 128
#define HID 1024
#define KCODES 1024

// =====================================================================
// TABLE GEMM BODY: 64x128 tile, BK=128, 4 waves (wave = 32x64 out).
// Purpose: ride-along decoder-table segments. BK=128 halves the serial
// {stage->drain->MFMA} count vs BK=64 (the tail latency when these
// blocks run after the main segment drains — round-8 lesson).
// k-slice fold order per output element: kb*128 + ks*32, ascending ==
// identical to the old BK=64 (kb*64 + h*32) order => outputs remain
// BIT-IDENTICAL to the previous table bodies.
// LDS: As 64x128 (16KB) @ lds[0], Bs 128x128 (32KB) @ lds[8192]. 48KB.
// Staging swizzle: slot (r, c in [0,16)) holds global chunk c^(r&15);
// reader XORs identically (the proven zvq et/zt pattern, 0 conflicts).
// OUTF=0: outb = f2bf(tanh(v)) ; OUTF=1: outf = v (f32).
// =====================================================================
template<int OUTF>
DEVI void tbl_body(ushort_t* lds, int f2,
                   const ushort_t* __restrict__ A, const ushort_t* __restrict__ Bt,
                   const float* __restrict__ bias, int K, int lnN, int N,
                   ushort_t* __restrict__ outb, float* __restrict__ outf)
{
  ushort_t* As = lds;            // [64*128]
  ushort_t* Bs = lds + 8192;     // [128*128]
  const int tid = threadIdx.x;
  const int w = tid >> 6, lane = tid & 63;
  const int lane15 = lane & 15, quad = lane >> 4;
  const int wr = w >> 1, wc = w & 1;
  const int m_idx = f2 >> lnN, n_idx = f2 & ((1 << lnN) - 1);
  const long m0 = (long)m_idx * 64;
  const int n0 = n_idx * 128;
  const int srow = lane >> 4, schk = lane & 15;

  f32x4 acc[2][4];
  #pragma unroll
  for (int i = 0; i < 2; i++)
    #pragma unroll
    for (int j = 0; j < 4; j++) acc[i][j] = (f32x4){0.f, 0.f, 0.f, 0.f};

  const int nk = K >> 7;
  for (int kb = 0; kb < nk; kb++){
    const int k0 = kb << 7;
    __syncthreads();
    #pragma unroll
    for (int s4 = 0; s4 < 4; s4++){
      int r = w * 16 + s4 * 4 + srow;
      async16(A + (m0 + r) * K + k0 + ((schk ^ (r & 15)) * 8), &As[(w * 16 + s4 * 4) * 128]);
    }
    #pragma unroll
    for (int s8 = 0; s8 < 8; s8++){
      int r = w * 32 + s8 * 4 + srow;
      async16(Bt + ((long)(n0 + r)) * K + k0 + ((schk ^ (r & 15)) * 8), &Bs[(w * 32 + s8 * 4) * 128]);
    }
    __builtin_amdgcn_s_waitcnt(0);
    __syncthreads();

    #pragma unroll
    for (int ks = 0; ks < 4; ks++){
      bf16x8 af[2], bf[4];
      #pragma unroll
      for (int i = 0; i < 2; i++){
        int rho = wr * 32 + i * 16 + lane15;
        af[i] = *(const bf16x8*)&As[rho * 128 + ((((ks << 2) | quad) ^ (rho & 15)) * 8)];
      }
      #pragma unroll
      for (int j = 0; j < 4; j++){
        int rho = wc * 64 + j * 16 + lane15;
        bf[j] = *(const bf16x8*)&Bs[rho * 128 + ((((ks << 2) | quad) ^ (rho & 15)) * 8)];
      }
      #pragma unroll
      for (int i = 0; i < 2; i++)
        #pragma unroll
        for (int j = 0; j < 4; j++)
          acc[i][j] = __builtin_amdgcn_mfma_f32_16x16x32_bf16(af[i], bf[j], acc[i][j], 0, 0, 0);
    }
  }

  #pragma unroll
  for (int i = 0; i < 2; i++){
    int row_l = wr * 32 + i * 16 + quad * 4;
    #pragma unroll
    for (int j = 0; j < 4; j++){
      int col = n0 + wc * 64 + j * 16 + lane15;
      float b = bias[col];
      #pragma unroll
      for (int r = 0; r < 4; r++){
        float v = acc[i][j][r] + b;
        if (OUTF == 0) outb[(m0 + row_l + r) * N + col] = f2bf(fast_tanh(v));
        else           outf[(m0 + row_l + r) * N + col] = v;
      }
    }
  }
}

// =====================================================================
// MERGED PREP (one launch): dtype flag + 6 weight transposes + action/emb
// cvt + biases + enorm. Every block computes the flag locally.
// =====================================================================
#define NTCVT 2816
__global__ void k_prep(const ushort_t* __restrict__ act16,
                       const void* __restrict__ act_src, ushort_t* __restrict__ act_dst,
                       const void* __restrict__ emb_src, ushort_t* __restrict__ emb_dst,
                       const void* b0, const void* b1, const void* b2,
                       const void* b3, const void* b4, const void* b5,
                       float* __restrict__ biasf, float* __restrict__ enorm,
                       const void* s0, ushort_t* d0, const void* s1, ushort_t* d1,
                       const void* s2, ushort_t* d2, const void* s3, ushort_t* d3,
                       const void* s4, ushort_t* d4, const void* s5, ushort_t* d5,
                       int* flagp){
  __shared__ ushort_t tile[32][33];
  __shared__ int redb[4];
  const int tid = threadIdx.x;

  int bad = 0;
  {
    float v = bf2f(act16[tid]);
    float a = fabsf(v);
    if (!(a <= 16.0f) || (a > 0.0f && a < 9.5e-7f)) bad = 1;
  }
  #pragma unroll
  for (int o = 32; o; o >>= 1) bad += __shfl_down(bad, o, 64);
  if ((tid & 63) == 0) redb[tid >> 6] = bad;
  __syncthreads();
  const int f = ((redb[0] + redb[1] + redb[2] + redb[3]) >= 8) ? 0 : 1;
  if (blockIdx.x == 0 && tid == 0) flagp[0] = f;
  __syncthreads();

  if (blockIdx.x < NTCVT){
    int t = blockIdx.x;
    const void* src; ushort_t* dst; int R, C, lcx;
    if (t < 256)      { src=s0; dst=d0; R=256;  C=1024; lcx=5; }
    else if (t < 1280){ src=s1; dst=d1; R=1024; C=1024; lcx=5; t-=256;  }
    else if (t < 1408){ src=s2; dst=d2; R=1024; C=128;  lcx=2; t-=1280; }
    else if (t < 1536){ src=s3; dst=d3; R=128;  C=1024; lcx=5; t-=1408; }
    else if (t < 2560){ src=s4; dst=d4; R=1024; C=1024; lcx=5; t-=1536; }
    else              { src=s5; dst=d5; R=1024; C=256;  lcx=3; t-=2560; }
    int bx = t & ((C >> 5) - 1), by = t >> lcx;
    int tx = tid & 31, ty = tid >> 5;
    int c = bx * 32 + tx;
    #pragma unroll
    for (int ii = 0; ii < 4; ii++){
      int r = by * 32 + ty + ii * 8;
      long idx = (long)r * C + c;
      tile[ty + ii * 8][tx] = f ? ((const ushort_t*)src)[idx] : f2bf(((const float*)src)[idx]);
    }
    __syncthreads();
    #pragma unroll
    for (int ii = 0; ii < 4; ii++){
      int cc = bx * 32 + ty + ii * 8;
      dst[(long)cc * R + by * 32 + tx] = tile[tx][ty + ii * 8];
    }
    return;
  }

  const int A8 = BB * INDIM / 8;
  const int E8 = KCODES * LATENT / 8;
  int i = (blockIdx.x - NTCVT) * blockDim.x + tid;
  if (i < A8 + E8){
    const void* src; ushort_t* dst; int k;
    if (i < A8){ src = act_src; dst = act_dst; k = i; }
    else       { src = emb_src; dst = emb_dst; k = i - A8; }
    if (f){
      ((uint4*)dst)[k] = ((const uint4*)src)[k];
    } else {
      const float* s = (const float*)src + (size_t)k * 8;
      ushort_t o[8];
      #pragma unroll
      for (int j = 0; j < 8; j++) o[j] = f2bf(s[j]);
      ((uint4*)dst)[k] = *(const uint4*)o;
    }
  } else {
    int k = i - A8 - E8;
    if (k < 6144){
      int seg = k >> 10, off = k & 1023;
      const void* sp; int n;
      switch (seg){
        case 0: sp = b0; n = 1024; break;
        case 1: sp = b1; n = 1024; break;
        case 2: sp = b2; n = 128;  break;
        case 3: sp = b3; n = 1024; break;
        case 4: sp = b4; n = 1024; break;
        default: sp = b5; n = 256; break;
      }
      if (off < n)
        biasf[seg * 1024 + off] = f ? bf2f(((const ushort_t*)sp)[off]) : ((const float*)sp)[off];
    } else if (k < 6144 + KCODES){
      int c = k - 6144;
      float s = 0.f;
      if (f){
        const ushort_t* e = (const ushort_t*)emb_src + (long)c * LATENT;
        for (int d = 0; d < LATENT; d++){ float v = bf2f(e[d]); s += v * v; }
      } else {
        const float* e = (const float*)emb_src + (long)c * LATENT;
        for (int d = 0; d < LATENT; d++){ float v = bf2f(f2bf(e[d])); s += v * v; }
      }
      enorm[c] = s;
    }
  }
}

// =====================================================================
// WIDE MFMA GEMM (N==1024): C = tanh(A[M,K] @ Bt[N,K]^T + b)
// 128x256 block tile, BK=64, main segment blocks [0,nblk1);
// table segment (64x128/BK=128 body) blocks [nblk1, grid) — LAST
// (round-7 A/B: small-first costs +8MB fetch, no makespan gain).
// =====================================================================
__global__ __launch_bounds__(256, 2)
void k_gemmw(const ushort_t* __restrict__ A, const ushort_t* __restrict__ Bt,
             const float* __restrict__ bias, int K,
             ushort_t* __restrict__ outb,
             int nblk1,
             const ushort_t* __restrict__ A2, const ushort_t* __restrict__ Bt2,
             const float* __restrict__ bias2, int K2,
             ushort_t* __restrict__ outb2)
{
  const int N = 1024;
  __shared__ __align__(16) ushort_t lds[24576];   // 48 KB shared pool
  const int tid = threadIdx.x;

  if ((int)blockIdx.x >= nblk1){
    tbl_body<0>(lds, blockIdx.x - nblk1, A2, Bt2, bias2, K2, 3, 1024, outb2, nullptr);
    return;
  }

  ushort_t* As = lds;            // [128*64] 16 KB
  ushort_t* Bs = lds + 8192;     // [256*64] 32 KB
  const int w = tid >> 6, lane = tid & 63;
  const int lane15 = lane & 15, quad = lane >> 4;
  const int wr = w >> 1, wc = w & 1;

  int f = blockIdx.x;
  const int j8 = f & 7, s = f >> 3;
  const int n_idx = s & 3;
  const int m_idx = ((s >> 2) << 3) | j8;
  const long m0 = (long)m_idx * 128;
  const int n0 = n_idx * 256;

  const int lrow = lane >> 3;
  const int lk8  = (((lane & 7) ^ (lrow & 7)) * 8);   // XOR-swizzled k-chunk
  const int rx   = lane15 & 7;

  f32x4 acc[4][8];
  #pragma unroll
  for (int i = 0; i < 4; i++)
    #pragma unroll
    for (int j = 0; j < 8; j++) acc[i][j] = (f32x4){0.f, 0.f, 0.f, 0.f};

  const int nk = K >> 6;
  for (int kb = 0; kb < nk; kb++){
    const int k0 = kb << 6;
    __syncthreads();
    #pragma unroll
    for (int a = 0; a < 4; a++){
      int m = w * 32 + a * 8 + lrow;
      async16(A + ((m0 + m) * K + k0 + lk8), &As[(w * 32 + a * 8) * 64]);
    }
    #pragma unroll
    for (int b = 0; b < 8; b++){
      int n = w * 64 + b * 8 + lrow;
      async16(Bt + ((long)(n0 + n) * K + k0 + lk8), &Bs[(w * 64 + b * 8) * 64]);
    }
    __builtin_amdgcn_s_waitcnt(0);
    __syncthreads();

    #pragma unroll
    for (int h = 0; h < 2; h++){
      bf16x8 af[4], bf[8];
      #pragma unroll
      for (int i = 0; i < 4; i++){
        int rho = wr * 64 + i * 16 + lane15;
        af[i] = *(const bf16x8*)&As[rho * 64 + ((((h << 2) | quad) ^ rx) * 8)];
      }
      #pragma unroll
      for (int j = 0; j < 8; j++){
        int rho = wc * 128 + j * 16 + lane15;
        bf[j] = *(const bf16x8*)&Bs[rho * 64 + ((((h << 2) | quad) ^ rx) * 8)];
      }
      #pragma unroll
      for (int i = 0; i < 4; i++)
        #pragma unroll
        for (int j = 0; j < 8; j++)
          acc[i][j] = __builtin_amdgcn_mfma_f32_16x16x32_bf16(af[i], bf[j], acc[i][j], 0, 0, 0);
    }
  }

  #pragma unroll
  for (int i = 0; i < 4; i++){
    int row_l = wr * 64 + i * 16 + quad * 4;
    #pragma unroll
    for (int j = 0; j < 8; j++){
      int col = n0 + wc * 128 + j * 16 + lane15;
      float b = bias[col];
      #pragma unroll
      for (int r = 0; r < 4; r++){
        float v = fast_tanh(acc[i][j][r] + b);
        outb[(m0 + row_l + r) * N + col] = f2bf(v);
      }
    }
  }
}

// =====================================================================
// FUSED z-GEMM + VQ (blocks [0,512)) + recon-table (blocks [512,544)).
// Main body: 64x128 z row-block (K=1024) -> z to d_out, f2bf(z) into
// swizzled zt LDS, stream 8 codebook tiles, running argmax, zq + codes
// + loss partial. Table body: rt[1024][256] = tB@dW2t^T + b, f32,
// 64x128/BK=128 body (32 blocks, nk=8 — halved tail).
// =====================================================================
__global__ __launch_bounds__(256)
void k_zvq(const ushort_t* __restrict__ A, const ushort_t* __restrict__ Bt,
           const float* __restrict__ bias, const ushort_t* __restrict__ embb,
           const float* __restrict__ enorm,
           int* __restrict__ codes, void* __restrict__ dout,
           long z_off, long zq_off,
           float* __restrict__ loss_part, const int* __restrict__ flagp,
           const ushort_t* __restrict__ tB, const ushort_t* __restrict__ dW2t,
           const float* __restrict__ bias3, float* __restrict__ rt)
{
  __shared__ __align__(16) ushort_t lds[24576];   // 48 KB
  __shared__ float lv[64][4];
  __shared__ int   li[64][4];
  __shared__ int   bi[64];
  __shared__ float red[4];

  const int tid = threadIdx.x;
  const int w = tid >> 6, lane = tid & 63;
  const int lane15 = lane & 15, quad = lane >> 4;
  const int wr = w >> 1, wc = w & 1;
  const int lrow = lane >> 3;
  const int rx   = lane15 & 7;

  if (blockIdx.x >= 512){
    tbl_body<1>(lds, blockIdx.x - 512, tB, dW2t, bias3, 1024, 1, 256, nullptr, rt);
    return;
  }

  ushort_t* As = lds;              // [64*64]   gemm phase
  ushort_t* Bs = lds + 4096;       // [128*64]  gemm phase
  ushort_t* zt = lds;              // [64*128]  vq phase
  ushort_t* et = lds + 8192;       // [128*128] vq phase

  const int f = blockIdx.x;
  const int j8 = f & 7, s = f >> 3;
  const int m_idx = (s << 3) | j8;
  const long m0 = (long)m_idx * 64;
  const int lk8  = (((lane & 7) ^ lrow) << 3);

  // ---------------- phase 1: z = A[64x1024] @ Bt[128][1024]^T ----------------
  f32x4 acc[2][4];
  #pragma unroll
  for (int i = 0; i < 2; i++)
    #pragma unroll
    for (int j = 0; j < 4; j++) acc[i][j] = (f32x4){0.f, 0.f, 0.f, 0.f};

  for (int kb = 0; kb < 16; kb++){
    const int k0 = kb << 6;
    __syncthreads();
    #pragma unroll
    for (int a = 0; a < 2; a++){
      int m = w * 16 + a * 8 + lrow;
      async16(A + ((m0 + m) * 1024 + k0 + lk8), &As[(w * 16 + a * 8) * 64]);
    }
    #pragma unroll
    for (int b = 0; b < 4; b++){
      int n = w * 32 + b * 8 + lrow;
      async16(Bt + ((long)n * 1024 + k0 + lk8), &Bs[(w * 32 + b * 8) * 64]);
    }
    __builtin_amdgcn_s_waitcnt(0);
    __syncthreads();

    #pragma unroll
    for (int h = 0; h < 2; h++){
      bf16x8 af[2], bf[4];
      #pragma unroll
      for (int i = 0; i < 2; i++){
        int rho = wr * 32 + i * 16 + lane15;
        af[i] = *(const bf16x8*)&As[rho * 64 + ((((h << 2) | quad) ^ rx) * 8)];
      }
      #pragma unroll
      for (int j = 0; j < 4; j++){
        int rho = wc * 64 + j * 16 + lane15;
        bf[j] = *(const bf16x8*)&Bs[rho * 64 + ((((h << 2) | quad) ^ rx) * 8)];
      }
      #pragma unroll
      for (int i = 0; i < 2; i++)
        #pragma unroll
        for (int j = 0; j < 4; j++)
          acc[i][j] = __builtin_amdgcn_mfma_f32_16x16x32_bf16(af[i], bf[j], acc[i][j], 0, 0, 0);
    }
  }

  const int fl = *flagp;
  #pragma unroll
  for (int i = 0; i < 2; i++){
    int row_l = wr * 32 + i * 16 + quad * 4;
    #pragma unroll
    for (int j = 0; j < 4; j++){
      int col = wc * 64 + j * 16 + lane15;
      float b = bias[col];
      #pragma unroll
      for (int r = 0; r < 4; r++){
        float v = acc[i][j][r] + b;
        acc[i][j][r] = v;
        long idx = (m0 + row_l + r) * 128 + col;
        if (fl) ((ushort_t*)dout)[z_off + idx] = f2bf(v);
        else    ((float*)dout)[z_off + idx] = v;
      }
    }
  }

  __syncthreads();   // all ds_reads of As/Bs retired; LDS repurposed below

  #pragma unroll
  for (int i = 0; i < 2; i++){
    #pragma unroll
    for (int j = 0; j < 4; j++){
      int col = wc * 64 + j * 16 + lane15;
      int g = col >> 3, cw = col & 7;
      #pragma unroll
      for (int r = 0; r < 4; r++){
        int row_l = wr * 32 + i * 16 + quad * 4 + r;
        zt[row_l * 128 + ((g ^ (row_l & 15)) << 3) + cw] = f2bf(acc[i][j][r]);
      }
    }
  }
  const int srow = lane >> 4, schk = lane & 15;
  #pragma unroll
  for (int s8 = 0; s8 < 8; s8++){
    int r = w * 32 + s8 * 4 + srow;
    async16(embb + (long)r * 128 + ((schk ^ (r & 15)) * 8), &et[(w * 32 + s8 * 4) * 128]);
  }
  __builtin_amdgcn_s_waitcnt(0);
  __syncthreads();

  // ---------------- phase 2: VQ scores + running argmax ----------------
  float bestv[16];
  int   bestc[16];
  #pragma unroll
  for (int u = 0; u < 16; u++){ bestv[u] = -1e30f; bestc[u] = 0; }

  for (int t = 0; t < 8; t++){
    f32x4 sacc[4][2];
    #pragma unroll
    for (int i = 0; i < 4; i++){
      sacc[i][0] = (f32x4){0.f, 0.f, 0.f, 0.f};
      sacc[i][1] = (f32x4){0.f, 0.f, 0.f, 0.f};
    }
    #pragma unroll
    for (int ks = 0; ks < 4; ks++){
      bf16x8 af[4], bf[2];
      #pragma unroll
      for (int i = 0; i < 4; i++){
        int rho = i * 16 + lane15;
        af[i] = *(const bf16x8*)&zt[rho * 128 + ((((ks << 2) | quad) ^ (rho & 15)) * 8)];
      }
      #pragma unroll
      for (int j = 0; j < 2; j++){
        int rho = w * 32 + j * 16 + lane15;
        bf[j] = *(const bf16x8*)&et[rho * 128 + ((((ks << 2) | quad) ^ (rho & 15)) * 8)];
      }
      #pragma unroll
      for (int i = 0; i < 4; i++)
        #pragma unroll
        for (int j = 0; j < 2; j++)
          sacc[i][j] = __builtin_amdgcn_mfma_f32_16x16x32_bf16(af[i], bf[j], sacc[i][j], 0, 0, 0);
    }
    #pragma unroll
    for (int i = 0; i < 4; i++)
      #pragma unroll
      for (int r = 0; r < 4; r++)
        #pragma unroll
        for (int j = 0; j < 2; j++){
          int code = t * 128 + w * 32 + j * 16 + lane15;
          float v = sacc[i][j][r] - 0.5f * enorm[code];
          int u = i * 4 + r;
          if (v > bestv[u]){ bestv[u] = v; bestc[u] = code; }
        }
    if (t < 7){
      __syncthreads();
      #pragma unroll
      for (int s8 = 0; s8 < 8; s8++){
        int r = w * 32 + s8 * 4 + srow;
        async16(embb + ((long)(t + 1) * 128 + r) * 128 + ((schk ^ (r & 15)) * 8),
                &et[(w * 32 + s8 * 4) * 128]);
      }
      __builtin_amdgcn_s_waitcnt(0);
      __syncthreads();
    }
  }

  #pragma unroll
  for (int i = 0; i < 4; i++)
    #pragma unroll
    for (int r = 0; r < 4; r++){
      float bv = bestv[i * 4 + r]; int bc = bestc[i * 4 + r];
      #pragma unroll
      for (int off = 1; off < 16; off <<= 1){
        float ov = __shfl_xor(bv, off, 64);
        int   oc = __shfl_xor(bc, off, 64);
        if (ov > bv || (ov == bv && oc < bc)){ bv = ov; bc = oc; }
      }
      if (lane15 == 0){
        int row_l = i * 16 + quad * 4 + r;
        lv[row_l][w] = bv; li[row_l][w] = bc;
      }
    }
  __syncthreads();
  if (tid < 64){
    float bv = lv[tid][0]; int bc = li[tid][0];
    #pragma unroll
    for (int ww = 1; ww < 4; ww++){
      float ov = lv[tid][ww]; int oc = li[tid][ww];
      if (ov > bv || (ov == bv && oc < bc)){ bv = ov; bc = oc; }
    }
    bi[tid] = bc;
    codes[m0 + tid] = bc;
  }
  __syncthreads();

  float p = 0.f;
  #pragma unroll
  for (int i = 0; i < 2; i++){
    #pragma unroll
    for (int j = 0; j < 4; j++){
      int col = wc * 64 + j * 16 + lane15;
      #pragma unroll
      for (int r = 0; r < 4; r++){
        int row_l = wr * 32 + i * 16 + quad * 4 + r;
        int code = bi[row_l];
        ushort_t qbits = embb[(long)code * LATENT + col];
        float qv = bf2f(qbits);
        long idx = (m0 + row_l) * LATENT + col;
        if (fl) ((ushort_t*)dout)[zq_off + idx] = qbits;
        else    ((float*)dout)[zq_off + idx] = qv;
        float diff = acc[i][j][r] - qv;
        p += diff * diff;
      }
    }
  }
  #pragma unroll
  for (int off = 32; off; off >>= 1) p += __shfl_down(p, off, 64);
  if ((tid & 63) == 0) red[tid >> 6] = p;
  __syncthreads();
  if (tid == 0) loss_part[blockIdx.x] = red[0] + red[1] + red[2] + red[3];
}

// =====================================================================
// recon gather + loss finalize fused: blocks [0,4096) gather
// out[row] = rt[codes[row]] (flag-dtype); block 4096 reduces loss_part.
// =====================================================================
__global__ __launch_bounds__(256)
void k_rgather(const float* __restrict__ rt, const int* __restrict__ codes,
               void* __restrict__ dout, const int* __restrict__ flagp,
               const float* __restrict__ loss_part, long l_off){
  const int fl = *flagp;
  if (blockIdx.x >= 4096){
    __shared__ float red[4];
    float s = 0.f;
    for (int i = threadIdx.x; i < 512; i += 256) s += loss_part[i];
    #pragma unroll
    for (int o = 32; o; o >>= 1) s += __shfl_down(s, o, 64);
    if ((threadIdx.x & 63) == 0) red[threadIdx.x >> 6] = s;
    __syncthreads();
    if (threadIdx.x == 0){
      float v = 1.25f * (red[0] + red[1] + red[2] + red[3]) / (float)((long)BB * LATENT);
      if (fl) ((ushort_t*)dout)[l_off] = f2bf(v);
      else    ((float*)dout)[l_off] = v;
    }
    return;
  }
  int row = blockIdx.x * 8 + (threadIdx.x >> 5);
  int c8 = (threadIdx.x & 31) * 8;
  int code = codes[row];
  const float* src = rt + (long)code * 256 + c8;
  float v[8];
  #pragma unroll
  for (int j = 0; j < 8; j++) v[j] = src[j];
  long base = (long)row * 256 + c8;
  if (fl){
    ushort_t o[8];
    #pragma unroll
    for (int j = 0; j < 8; j++) o[j] = f2bf(v[j]);
    *(uint4*)((ushort_t*)dout + base) = *(const uint4*)o;
  } else {
    float* d = (float*)dout + base;
    *(float4*)d = *(const float4*)v;
    *(float4*)(d + 4) = *(const float4*)(v + 4);
  }
}

// =====================================================================
extern "C" void kernel_launch(void* const* d_in, const int* in_sizes, int n_in,
                              void* d_out, int out_size, void* d_ws, size_t ws_size,
                              hipStream_t stream)
{
  (void)in_sizes; (void)n_in; (void)out_size; (void)ws_size;
  const void* action = d_in[1];
  const void* eW0 = d_in[2];  const void* eb0 = d_in[3];
  const void* eW1 = d_in[4];  const void* eb1 = d_in[5];
  const void* eW2 = d_in[6];  const void* eb2 = d_in[7];
  const void* emb = d_in[8];
  const void* dW0 = d_in[9];  const void* db0 = d_in[10];
  const void* dW1 = d_in[11]; const void* db1 = d_in[12];
  const void* dW2 = d_in[13]; const void* db2 = d_in[14];

  char* ws = (char*)d_ws;
  size_t off = 0;
  auto alloc = [&](size_t bytes)->char*{
    char* p = ws + off; off += bytes; off = (off + 255) & ~((size_t)255); return p;
  };
  int*      flag     = (int*)  alloc(4);
  float*    biasf    = (float*)alloc(6 * 1024 * 4);
  float*    enorm    = (float*)alloc(KCODES * 4);
  ushort_t* eW0t = (ushort_t*)alloc((size_t)HID * INDIM * 2);
  ushort_t* eW1t = (ushort_t*)alloc((size_t)HID * HID * 2);
  ushort_t* eW2t = (ushort_t*)alloc((size_t)LATENT * HID * 2);
  ushort_t* embb = (ushort_t*)alloc((size_t)KCODES * LATENT * 2);
  ushort_t* dW0t = (ushort_t*)alloc((size_t)HID * LATENT * 2);
  ushort_t* dW1t = (ushort_t*)alloc((size_t)HID * HID * 2);
  ushort_t* dW2t = (ushort_t*)alloc((size_t)INDIM * HID * 2);
  ushort_t* act0 = (ushort_t*)alloc((size_t)BB * INDIM * 2);
  ushort_t* hA   = (ushort_t*)alloc((size_t)BB * HID * 2);
  ushort_t* hB   = (ushort_t*)alloc((size_t)BB * HID * 2);
  ushort_t* tA   = (ushort_t*)alloc((size_t)KCODES * HID * 2);   // decoder table L0
  ushort_t* tB   = (ushort_t*)alloc((size_t)KCODES * HID * 2);   // decoder table L1
  float*    rt   = (float*)   alloc((size_t)KCODES * INDIM * 4); // recon table (f32)
  int*      codes = (int*)    alloc((size_t)BB * 4);
  float*    loss_part = (float*)alloc((size_t)512 * 4);

  const long z_off  = (long)BB * INDIM;
  const long zq_off = z_off + (long)BB * LATENT;
  const long l_off  = zq_off + (long)BB * LATENT;

  // ---- merged prep: transposes + cvt + bias + enorm + dtype flag (1 launch) ----
  {
    const int A8 = BB * INDIM / 8, E8 = KCODES * LATENT / 8;
    int nprep = (A8 + E8 + 6144 + KCODES + 255) / 256;
    k_prep<<<NTCVT + nprep, 256, 0, stream>>>((const ushort_t*)action,
        action, act0, emb, embb,
        eb0, eb1, eb2, db0, db1, db2, biasf, enorm,
        eW0, eW0t, eW1, eW1t, eW2, eW2t,
        dW0, dW0t, dW1, dW1t, dW2, dW2t, flag);
  }

  // ---- enc-L0 (K=256, 1024 blk) + table L0 (K=128, 128 blk, nk=1, LAST) ----
  k_gemmw<<<1152, 256, 0, stream>>>(act0, eW0t, biasf + 0, INDIM, hA,
      1024, embb, dW0t, biasf + 3072, LATENT, tA);

  // ---- enc-L1 (K=1024, 1024 blk) + table L1 (K=1024, 128 blk, nk=8, LAST) ----
  k_gemmw<<<1152, 256, 0, stream>>>(hA, eW1t, biasf + 1024, HID, hB,
      1024, tA, dW1t, biasf + 4096, HID, tB);

  // ---- fused z-GEMM + VQ (512 blk) + recon table (32 blk, nk=8, LAST) ----
  k_zvq<<<544, 256, 0, stream>>>(hB, eW2t, biasf + 2048, embb, enorm,
      codes, d_out, z_off, zq_off, loss_part, flag,
      tB, dW2t, biasf + 5120, rt);

  // ---- decoder = table gather (+ loss finalize in last block) ----
  k_rgather<<<BB / 8 + 1, 256, 0, stream>>>(rt, codes, d_out, flag, loss_part, l_off);
}